// Round 15
// baseline (212.103 us; speedup 1.0000x reference)
//
#include <hip/hip_runtime.h>
#include <hip/hip_bf16.h>
#include <stdint.h>

typedef __attribute__((ext_vector_type(4))) int i32x4;
typedef __attribute__((ext_vector_type(16))) int i32x16;
typedef signed char s8;

#define M_TOT 8192
#define N_TOT 8192
#define K_TOT 2048
#define W_COUNT (N_TOT * K_TOT)
#define X_COUNT (M_TOT * K_TOT)

// ---------------- 1. fused deterministic reductions: sum|w| (double), max|x| ----------
__global__ void tl_reduce(const float* __restrict__ w, const float* __restrict__ x,
                          double* __restrict__ wsum, float* __restrict__ xmax) {
    const int b = blockIdx.x;
    if (b < 1024) {
        const int tid = b * 256 + threadIdx.x;
        const float4* w4 = (const float4*)w;
        double s = 0.0;
        for (int i = tid; i < W_COUNT / 4; i += 1024 * 256) {
            float4 v = w4[i];
            s += (double)fabsf(v.x) + (double)fabsf(v.y) + (double)fabsf(v.z) + (double)fabsf(v.w);
        }
        #pragma unroll
        for (int off = 32; off > 0; off >>= 1) s += __shfl_down(s, off);
        __shared__ double red[4];
        if ((threadIdx.x & 63) == 0) red[threadIdx.x >> 6] = s;
        __syncthreads();
        if (threadIdx.x == 0) wsum[b] = (red[0] + red[1]) + (red[2] + red[3]);
    } else {
        const int tid = (b - 1024) * 256 + threadIdx.x;
        const float4* x4 = (const float4*)x;
        float m = 0.0f;
        for (int i = tid; i < X_COUNT / 4; i += 1024 * 256) {
            float4 v = x4[i];
            m = fmaxf(m, fmaxf(fmaxf(fabsf(v.x), fabsf(v.y)), fmaxf(fabsf(v.z), fabsf(v.w))));
        }
        #pragma unroll
        for (int off = 32; off > 0; off >>= 1) m = fmaxf(m, __shfl_down(m, off));
        __shared__ float redm[4];
        if ((threadIdx.x & 63) == 0) redm[threadIdx.x >> 6] = m;
        __syncthreads();
        if (threadIdx.x == 0) xmax[b - 1024] = fmaxf(fmaxf(redm[0], redm[1]), fmaxf(redm[2], redm[3]));
    }
}

__global__ void tl_finalize(const double* __restrict__ wsum, const float* __restrict__ xmax,
                            const float* __restrict__ alpha,
                            double* __restrict__ delta, float* __restrict__ qp) {
    const int t = threadIdx.x;
    double s = (wsum[t] + wsum[t + 256]) + (wsum[t + 512] + wsum[t + 768]);
    float m = fmaxf(fmaxf(xmax[t], xmax[t + 256]), fmaxf(xmax[t + 512], xmax[t + 768]));
    #pragma unroll
    for (int off = 32; off > 0; off >>= 1) {
        s += __shfl_down(s, off);
        m = fmaxf(m, __shfl_down(m, off));
    }
    __shared__ double rs[4];
    __shared__ float rm[4];
    if ((t & 63) == 0) { rs[t >> 6] = s; rm[t >> 6] = m; }
    __syncthreads();
    if (t == 0) {
        *delta = 0.7 * (((rs[0] + rs[1]) + (rs[2] + rs[3])) / (double)W_COUNT);
        float mm = fmaxf(fmaxf(rm[0], rm[1]), fmaxf(rm[2], rm[3]));
        qp[0] = 127.0f / mm;                   // x quant scale
        qp[1] = alpha[0] * (mm / 127.0f);      // output scale
    }
}

// ---------------- 2. ternarize w -> i8 {-1,0,+1} (row-major) ----------------
__global__ void tl_tern_w(const float* __restrict__ w, const double* __restrict__ delta_p,
                          s8* __restrict__ wb) {
    const double d = *delta_p;
    const int i = (blockIdx.x * 256 + threadIdx.x) * 16;
    union { s8 c[16]; i32x4 v; } o;
    #pragma unroll
    for (int j = 0; j < 16; j += 4) {
        float4 v = *(const float4*)(w + i + j);
        float f[4] = {v.x, v.y, v.z, v.w};
        #pragma unroll
        for (int r = 0; r < 4; ++r) {
            double wd = (double)f[r];
            o.c[j + r] = wd > d ? 1 : (wd < -d ? -1 : 0);
        }
    }
    *(i32x4*)(wb + i) = o.v;
}

// ---------------- 3. quantize x -> i8 (RNE, clamp 127), row-major ----------------
__global__ void tl_quant_x(const float* __restrict__ x, const float* __restrict__ qp,
                           s8* __restrict__ xb) {
    const float inv = qp[0];
    const int i = (blockIdx.x * 256 + threadIdx.x) * 16;
    union { s8 c[16]; i32x4 v; } o;
    #pragma unroll
    for (int j = 0; j < 16; j += 4) {
        float4 v = *(const float4*)(x + i + j);
        float f[4] = {v.x, v.y, v.z, v.w};
        #pragma unroll
        for (int r = 0; r < 4; ++r) {
            int q = (int)__builtin_rintf(f[r] * inv);
            q = q > 127 ? 127 : (q < -127 ? -127 : q);
            o.c[j + r] = (s8)q;
        }
    }
    *(i32x4*)(xb + i) = o.v;
}

// ---------------- 4. i8 MFMA GEMM, 256x256, 8-PHASE fine interleave (m201 port) ----
// C[m][n] = out_scale * (sum_k xq[m][k]*wt[n][k]) + bias[n]
// 512 threads = 8 waves (2 wr x 4 wc); wave owns 128x64 = 4x2 32x32 frags.
// LDS: 3 slots/operand (A: s*16K, B: 49152+s*16K), 96 KiB; stage t+2.
// Per K-tile: 4 fine phases, each {2-4 ds_read (same-phase consume) + 1 glds;
// SB; BARR; LGKM0; SB; setprio1; 4 MFMA; setprio0; BARR}. MFMA split:
// ph1 m01*kk0, ph2 m23*kk0, ph3 m01*kk1, ph4 m23*kk1; bC=kk0 (ph1), bD=kk1 (ph2).
// Counted VMW(4) only at ph4 (retires t+1 staging, issued a full tile ago).

#define SB    __builtin_amdgcn_sched_barrier(0)
#define BARR  __builtin_amdgcn_s_barrier()
#define LGKM0 asm volatile("s_waitcnt lgkmcnt(0)" ::: "memory")
#define VMW(N) asm volatile("s_waitcnt vmcnt(" #N ")" ::: "memory")
#define PRIO1 __builtin_amdgcn_s_setprio(1)
#define PRIO0 __builtin_amdgcn_s_setprio(0)

#define GLDS(SRC, DOFF) __builtin_amdgcn_global_load_lds(                      \
    (const __attribute__((address_space(1))) void*)(SRC),                      \
    (__attribute__((address_space(3))) void*)(lds + (DOFF)), 16, 0, 0)

// 2 A-frag reads (m = MB, MB+1) for k-half KK of slot S
#define RD_A2(AR, S, MB, KK) do {                                              \
    AR[0] = *(const i32x4*)(lds + (S) * 16384 + wrOff + ((MB) + 0) * 2048 +    \
                            (lrd ^ ((KK) * 32)));                              \
    AR[1] = *(const i32x4*)(lds + (S) * 16384 + wrOff + ((MB) + 1) * 2048 +    \
                            (lrd ^ ((KK) * 32)));                              \
} while (0)
// 2 B-frag reads (n = 0,1) for k-half KK of slot S
#define RD_B2(BR, S, KK) do {                                                  \
    BR[0] = *(const i32x4*)(lds + 49152 + (S) * 16384 + wcOff + 0 * 2048 +     \
                            (lrd ^ ((KK) * 32)));                              \
    BR[1] = *(const i32x4*)(lds + 49152 + (S) * 16384 + wcOff + 1 * 2048 +     \
                            (lrd ^ ((KK) * 32)));                              \
} while (0)

// 4 MFMA: rows MB,MB+1 x cols 0,1
#define MM4(AR, BR, MB) do {                                                   \
    acc[(MB)][0]     = __builtin_amdgcn_mfma_i32_32x32x32_i8(AR[0], BR[0], acc[(MB)][0], 0, 0, 0);     \
    acc[(MB)][1]     = __builtin_amdgcn_mfma_i32_32x32x32_i8(AR[0], BR[1], acc[(MB)][1], 0, 0, 0);     \
    acc[(MB) + 1][0] = __builtin_amdgcn_mfma_i32_32x32x32_i8(AR[1], BR[0], acc[(MB) + 1][0], 0, 0, 0); \
    acc[(MB) + 1][1] = __builtin_amdgcn_mfma_i32_32x32x32_i8(AR[1], BR[1], acc[(MB) + 1][1], 0, 0, 0); \
} while (0)

// K-tile = 4 phases; slot S; stage tile t+2 into SG (1 glds per phase)
#define KT8(S, SG, KOFF, DOSTG, GATE) do {                                     \
    /* ph1: m01 x kk0 */                                                       \
    RD_A2(aP, S, 0, 0); RD_B2(bC, S, 0);                                       \
    if (DOSTG) GLDS(aSrc + (KOFF), (SG) * 16384 + L);                          \
    SB; BARR; LGKM0; SB;                                                       \
    PRIO1; MM4(aP, bC, 0); PRIO0; BARR;                                        \
    /* ph2: m23 x kk0 (loads bD = kk1 for ph3/4) */                            \
    RD_A2(aQ, S, 2, 0); RD_B2(bD, S, 1);                                       \
    if (DOSTG) GLDS(aSrc + (KOFF) + 262144, (SG) * 16384 + 8192 + L);          \
    SB; BARR; LGKM0; SB;                                                       \
    PRIO1; MM4(aQ, bC, 2); PRIO0; BARR;                                        \
    /* ph3: m01 x kk1 */                                                       \
    RD_A2(aP, S, 0, 1);                                                        \
    if (DOSTG) GLDS(bSrc + (KOFF), 49152 + (SG) * 16384 + L);                  \
    SB; BARR; LGKM0; SB;                                                       \
    PRIO1; MM4(aP, bD, 0); PRIO0; BARR;                                        \
    /* ph4: m23 x kk1; counted gate */                                         \
    RD_A2(aQ, S, 2, 1);                                                        \
    if (DOSTG) GLDS(bSrc + (KOFF) + 262144, 49152 + (SG) * 16384 + 8192 + L);  \
    SB; BARR; LGKM0; SB;                                                       \
    PRIO1; MM4(aQ, bD, 2); PRIO0;                                              \
    GATE; BARR;                                                                \
} while (0)

__global__ __launch_bounds__(512, 2) void tl_gemm_i8(
    const s8* __restrict__ A, const s8* __restrict__ Bm,
    const float* __restrict__ qp, const float* __restrict__ bias,
    float* __restrict__ C) {
    __shared__ __attribute__((aligned(128))) char lds[98304];  // 96 KiB

    const int t = threadIdx.x;
    const int wid = t >> 6;
    const int l = t & 63;
    const int wr = wid >> 2;   // 0..1
    const int wc = wid & 3;    // 0..3

    // rect XCD ordering: resident 32 blocks/XCD = 4tm x 8tn rectangle
    const int bid = blockIdx.x;
    const int xc = bid & 7;
    const int j = bid >> 3;                       // 0..127
    const int tm = xc * 4 + ((j >> 3) & 3);
    const int tn = (j >> 5) * 8 + (j & 7);
    const int row0 = tm * 256, col0 = tn * 256;

    // staging coords: linear LDS dest byte L holds logical offset
    // off = L ^ (((L>>7)&3)<<4)  i.e. col-chunk ^= (row>>1)&3 (involution)
    const int L = t * 16;
    const int off = L ^ (((L >> 7) & 3) << 4);
    const int sr = off >> 6;          // 0..127 (row within half)
    const int kb = off & 63;          // 16-aligned k-byte
    const s8* aSrc = A + (size_t)(row0 + sr) * K_TOT + kb;
    const s8* bSrc = Bm + (size_t)(col0 + sr) * K_TOT + kb;

    // ds_read lane constants (32x32 fragment: row = l&31, k-group = l>>5)
    const int rl = l & 31, kg = l >> 5;
    const int lrd = rl * 64 + ((kg ^ ((rl >> 1) & 3)) << 4);
    const int wrOff = wr * 8192;      // 128 rows * 64 B
    const int wcOff = wc * 4096;      // 64 rows * 64 B

    i32x16 acc[4][2] = {};
    i32x4 aP[2], aQ[2], bC[2], bD[2];

    // prologue: stage tiles 0 (slot0) and 1 (slot1); gate tile0
    GLDS(aSrc, 0 + L);                 GLDS(aSrc + 262144, 8192 + L);
    GLDS(bSrc, 49152 + L);             GLDS(bSrc + 262144, 49152 + 8192 + L);
    GLDS(aSrc + 64, 16384 + L);        GLDS(aSrc + 64 + 262144, 16384 + 8192 + L);
    GLDS(bSrc + 64, 49152 + 16384 + L);
    GLDS(bSrc + 64 + 262144, 49152 + 16384 + 8192 + L);
    VMW(4); SB; BARR;

    int koff = 128;   // staging byte offset for tile t+2
    #pragma unroll 1
    for (int i = 0; i < 10; ++i) {
        KT8(0, 2, koff, 1, VMW(4)); koff += 64;
        KT8(1, 0, koff, 1, VMW(4)); koff += 64;
        KT8(2, 1, koff, 1, VMW(4)); koff += 64;
    }
    KT8(0, 0, 0, 0, VMW(0));    // tile 30: drain t31 staging
    KT8(1, 0, 0, 0, (void)0);   // tile 31

    // epilogue: C = out_scale * acc + bias
    // 32x32 C/D layout: col = l&31, row = (reg&3) + 8*(reg>>2) + 4*(l>>5)
    const float osc = qp[1];
    #pragma unroll
    for (int m_ = 0; m_ < 4; ++m_) {
        const int crow = row0 + wr * 128 + m_ * 32 + kg * 4;
        #pragma unroll
        for (int n_ = 0; n_ < 2; ++n_) {
            const int ccol = col0 + wc * 64 + n_ * 32 + rl;
            const float bv = bias[ccol];
            #pragma unroll
            for (int r = 0; r < 16; ++r) {
                const int row = crow + (r & 3) + 8 * (r >> 2);
                C[(size_t)row * N_TOT + ccol] = (float)acc[m_][n_][r] * osc + bv;
            }
        }
    }
}

extern "C" void kernel_launch(void* const* d_in, const int* in_sizes, int n_in,
                              void* d_out, int out_size, void* d_ws, size_t ws_size,
                              hipStream_t stream) {
    const float* x     = (const float*)d_in[0];
    const float* wgt   = (const float*)d_in[1];
    const float* alpha = (const float*)d_in[2];
    const float* bias  = (const float*)d_in[3];
    float* out = (float*)d_out;

    char* ws = (char*)d_ws;
    double* wsum = (double*)ws;               // 8 KB
    float* xmax  = (float*)(ws + 8192);       // 4 KB
    double* delta = (double*)(ws + 12288);
    float* qp     = (float*)(ws + 12304);     // [0]=127/max, [1]=alpha*max/127
    s8* xb = (s8*)(ws + 16384);               // 16 MB, row-major
    s8* wb = (s8*)(ws + 16384 + (size_t)X_COUNT);  // 16 MB, row-major

    tl_reduce<<<2048, 256, 0, stream>>>(wgt, x, wsum, xmax);
    tl_finalize<<<1, 256, 0, stream>>>(wsum, xmax, alpha, delta, qp);
    tl_tern_w<<<W_COUNT / (256 * 16), 256, 0, stream>>>(wgt, delta, wb);
    tl_quant_x<<<X_COUNT / (256 * 16), 256, 0, stream>>>(x, qp, xb);
    tl_gemm_i8<<<(M_TOT / 256) * (N_TOT / 256), 512, 0, stream>>>(xb, wb, qp, bias, out);
}

// Round 16
// 200.656 us; speedup vs baseline: 1.0571x; 1.0571x over previous
//
#include <hip/hip_runtime.h>
#include <hip/hip_bf16.h>
#include <stdint.h>

typedef __attribute__((ext_vector_type(4))) int i32x4;
typedef __attribute__((ext_vector_type(16))) int i32x16;
typedef signed char s8;

#define M_TOT 8192
#define N_TOT 8192
#define K_TOT 2048
#define W_COUNT (N_TOT * K_TOT)
#define X_COUNT (M_TOT * K_TOT)

// ---------------- 1. fused deterministic reductions: sum|w| (double), max|x| ----------
__global__ void tl_reduce(const float* __restrict__ w, const float* __restrict__ x,
                          double* __restrict__ wsum, float* __restrict__ xmax) {
    const int b = blockIdx.x;
    if (b < 1024) {
        const int tid = b * 256 + threadIdx.x;
        const float4* w4 = (const float4*)w;
        double s = 0.0;
        for (int i = tid; i < W_COUNT / 4; i += 1024 * 256) {
            float4 v = w4[i];
            s += (double)fabsf(v.x) + (double)fabsf(v.y) + (double)fabsf(v.z) + (double)fabsf(v.w);
        }
        #pragma unroll
        for (int off = 32; off > 0; off >>= 1) s += __shfl_down(s, off);
        __shared__ double red[4];
        if ((threadIdx.x & 63) == 0) red[threadIdx.x >> 6] = s;
        __syncthreads();
        if (threadIdx.x == 0) wsum[b] = (red[0] + red[1]) + (red[2] + red[3]);
    } else {
        const int tid = (b - 1024) * 256 + threadIdx.x;
        const float4* x4 = (const float4*)x;
        float m = 0.0f;
        for (int i = tid; i < X_COUNT / 4; i += 1024 * 256) {
            float4 v = x4[i];
            m = fmaxf(m, fmaxf(fmaxf(fabsf(v.x), fabsf(v.y)), fmaxf(fabsf(v.z), fabsf(v.w))));
        }
        #pragma unroll
        for (int off = 32; off > 0; off >>= 1) m = fmaxf(m, __shfl_down(m, off));
        __shared__ float redm[4];
        if ((threadIdx.x & 63) == 0) redm[threadIdx.x >> 6] = m;
        __syncthreads();
        if (threadIdx.x == 0) xmax[b - 1024] = fmaxf(fmaxf(redm[0], redm[1]), fmaxf(redm[2], redm[3]));
    }
}

__global__ void tl_finalize(const double* __restrict__ wsum, const float* __restrict__ xmax,
                            const float* __restrict__ alpha,
                            double* __restrict__ delta, float* __restrict__ qp) {
    const int t = threadIdx.x;
    double s = (wsum[t] + wsum[t + 256]) + (wsum[t + 512] + wsum[t + 768]);
    float m = fmaxf(fmaxf(xmax[t], xmax[t + 256]), fmaxf(xmax[t + 512], xmax[t + 768]));
    #pragma unroll
    for (int off = 32; off > 0; off >>= 1) {
        s += __shfl_down(s, off);
        m = fmaxf(m, __shfl_down(m, off));
    }
    __shared__ double rs[4];
    __shared__ float rm[4];
    if ((t & 63) == 0) { rs[t >> 6] = s; rm[t >> 6] = m; }
    __syncthreads();
    if (t == 0) {
        *delta = 0.7 * (((rs[0] + rs[1]) + (rs[2] + rs[3])) / (double)W_COUNT);
        float mm = fmaxf(fmaxf(rm[0], rm[1]), fmaxf(rm[2], rm[3]));
        qp[0] = 127.0f / mm;                   // x quant scale
        qp[1] = alpha[0] * (mm / 127.0f);      // output scale
    }
}

// ---------------- 2. fused quantize: w -> ternary i8, x -> i8 (one dispatch) --------
__global__ void tl_quant(const float* __restrict__ w, const float* __restrict__ x,
                         const double* __restrict__ delta_p, const float* __restrict__ qp,
                         s8* __restrict__ wb, s8* __restrict__ xb) {
    const int b = blockIdx.x;
    if (b < 4096) {
        const double d = *delta_p;
        const int i = (b * 256 + threadIdx.x) * 16;
        union { s8 c[16]; i32x4 v; } o;
        #pragma unroll
        for (int j = 0; j < 16; j += 4) {
            float4 v = *(const float4*)(w + i + j);
            float f[4] = {v.x, v.y, v.z, v.w};
            #pragma unroll
            for (int r = 0; r < 4; ++r) {
                double wd = (double)f[r];
                o.c[j + r] = wd > d ? 1 : (wd < -d ? -1 : 0);
            }
        }
        *(i32x4*)(wb + i) = o.v;
    } else {
        const float inv = qp[0];
        const int i = ((b - 4096) * 256 + threadIdx.x) * 16;
        union { s8 c[16]; i32x4 v; } o;
        #pragma unroll
        for (int j = 0; j < 16; j += 4) {
            float4 v = *(const float4*)(x + i + j);
            float f[4] = {v.x, v.y, v.z, v.w};
            #pragma unroll
            for (int r = 0; r < 4; ++r) {
                int q = (int)__builtin_rintf(f[r] * inv);
                q = q > 127 ? 127 : (q < -127 ? -127 : q);
                o.c[j + r] = (s8)q;
            }
        }
        *(i32x4*)(xb + i) = o.v;
    }
}

// ---------------- 3. i8 MFMA GEMM, 256x256, BK=128, minimal-sync skeleton ----------
// C[m][n] = out_scale * (sum_k xq[m][k]*wt[n][k]) + bias[n]
// 512 threads = 8 waves (2 wr x 4 wc); wave owns 128x64 = 4x2 32x32 frags.
// LDS 128 KiB: A slots 0/32K, B slots 64K/96K (each 256 rows x 128 B).
// Swizzle (128-B rows): physical chunk16 = logical chunk16 ^ (row&7).
// Per K-tile (K=128): 4 quarters q0..q3; reads for q+1 issued under MFMA(q);
// stage t+1 (8 glds) spread over q1/q2 windows; ONE VMW(0)+BARR per tile
// (loads >=600 cyc old at gate). Sync density: 1 barrier + 4 counted lgkm
// per 1171 MFMA-cyc/wave -- half of r7's. No setprio (r14 null).

#define SB    __builtin_amdgcn_sched_barrier(0)
#define BARR  __builtin_amdgcn_s_barrier()
#define LGKM6 asm volatile("s_waitcnt lgkmcnt(6)" ::: "memory")
#define LGKM0 asm volatile("s_waitcnt lgkmcnt(0)" ::: "memory")
#define VMW(N) asm volatile("s_waitcnt vmcnt(" #N ")" ::: "memory")

#define GLDS(SRC, DOFF) __builtin_amdgcn_global_load_lds(                      \
    (const __attribute__((address_space(1))) void*)(SRC),                      \
    (__attribute__((address_space(3))) void*)(lds + (DOFF)), 16, 0, 0)

// 6 reads (4 A + 2 B) for k-quarter Q of A-slot SA / B-slot SB_
#define RD6(AR, BR, SA, SB_, Q) do {                                           \
    _Pragma("unroll") for (int m_ = 0; m_ < 4; ++m_)                           \
        AR[m_] = *(const i32x4*)(lds + (SA) + wrOff + m_ * 4096 +              \
                                 (((Q) * 32 + kg16) ^ xr));                    \
    _Pragma("unroll") for (int n_ = 0; n_ < 2; ++n_)                           \
        BR[n_] = *(const i32x4*)(lds + (SB_) + wcOff + n_ * 4096 +             \
                                 (((Q) * 32 + kg16) ^ xr));                    \
} while (0)

#define MM8(AR, BR) do {                                                       \
    _Pragma("unroll") for (int m_ = 0; m_ < 4; ++m_)                           \
    _Pragma("unroll") for (int n_ = 0; n_ < 2; ++n_)                           \
        acc[m_][n_] = __builtin_amdgcn_mfma_i32_32x32x32_i8(                   \
            AR[m_], BR[n_], acc[m_][n_], 0, 0, 0);                             \
} while (0)

// stage one 32-KB slot: 4 glds calls (8 KB each; 64 rows per call)
#define STG_A2(DS, KOFF, J0) do {                                              \
    GLDS(aSrc + (size_t)((J0) * 64) * K_TOT + (KOFF), (DS) + (J0) * 8192 + L); \
    GLDS(aSrc + (size_t)(((J0) + 1) * 64) * K_TOT + (KOFF),                    \
         (DS) + ((J0) + 1) * 8192 + L);                                        \
} while (0)
#define STG_B2(DS, KOFF, J0) do {                                              \
    GLDS(bSrc + (size_t)((J0) * 64) * K_TOT + (KOFF), (DS) + (J0) * 8192 + L); \
    GLDS(bSrc + (size_t)(((J0) + 1) * 64) * K_TOT + (KOFF),                    \
         (DS) + ((J0) + 1) * 8192 + L);                                        \
} while (0)

// One K-tile: A slot SA, B slot SBs (current); stage t+1 into the other pair.
// Entering invariant: q0 reads (aE/bE) in flight.
#define KT(SA, SBs, SAN, SBN, KOFF, DOSTG, GATE, DONEXT) do {                  \
    RD6(aO, bO, SA, SBs, 1);                                                   \
    LGKM6; SB;                                                                 \
    MM8(aE, bE);                         /* q0 */                              \
    if (DOSTG) { STG_A2(SAN, KOFF, 0); STG_A2(SAN, KOFF, 2); }                 \
    RD6(aE, bE, SA, SBs, 2);                                                   \
    LGKM6; SB;                                                                 \
    MM8(aO, bO);                         /* q1 */                              \
    if (DOSTG) { STG_B2(SBN, KOFF, 0); STG_B2(SBN, KOFF, 2); }                 \
    RD6(aO, bO, SA, SBs, 3);                                                   \
    LGKM6; SB;                                                                 \
    MM8(aE, bE);                         /* q2 */                              \
    LGKM0; SB;                                                                 \
    GATE; SB;                                                                  \
    BARR;                                                                      \
    if (DONEXT) RD6(aE, bE, SAN, SBN, 0);                                      \
    MM8(aO, bO);                         /* q3 */                              \
} while (0)

__global__ __launch_bounds__(512, 2) void tl_gemm_i8(
    const s8* __restrict__ A, const s8* __restrict__ Bm,
    const float* __restrict__ qp, const float* __restrict__ bias,
    float* __restrict__ C) {
    __shared__ __attribute__((aligned(128))) char lds[131072];  // 128 KiB

    const int t = threadIdx.x;
    const int wid = t >> 6;
    const int l = t & 63;
    const int wr = wid >> 2;   // 0..1
    const int wc = wid & 3;    // 0..3

    // rect XCD ordering: resident 32 blocks/XCD = 4tm x 8tn rectangle (r7)
    const int bid = blockIdx.x;
    const int xc = bid & 7;
    const int j = bid >> 3;                       // 0..127
    const int tm = xc * 4 + ((j >> 3) & 3);
    const int tn = (j >> 5) * 8 + (j & 7);
    const int row0 = tm * 256, col0 = tn * 256;

    // staging: linear dest byte D = j*8192 + t*16 holds logical
    // off = D ^ (((D>>7)&7)<<4): row = t>>3 (+64 per call), col = ((t&7)<<4)^(((t>>3)&7)<<4)
    const int L = t * 16;
    const int sr = t >> 3;                          // 0..63
    const int kb = ((t & 7) << 4) ^ (((t >> 3) & 7) << 4);
    const s8* aSrc = A + (size_t)(row0 + sr) * K_TOT + kb;
    const s8* bSrc = Bm + (size_t)(col0 + sr) * K_TOT + kb;

    // read lane constants: row = rl (l&31), chunk16 = (q*2+kg) ^ (rl&7)
    const int rl = l & 31, kg = l >> 5;
    const int kg16 = kg * 16;
    const int xr = (rl & 7) << 4;
    const int wrOff = wr * 128 * 128 + rl * 128;   // wave A rows (128 B/row)
    const int wcOff = wc * 64 * 128 + rl * 128;    // wave B rows

    i32x16 acc[4][2] = {};
    i32x4 aE[4], bE[2], aO[4], bO[2];

    // prologue: stage tile 0 into slots A0/B0; gate; first q0 reads
    STG_A2(0, 0, 0); STG_A2(0, 0, 2);
    STG_B2(65536, 0, 0); STG_B2(65536, 0, 2);
    VMW(0); SB; BARR;
    RD6(aE, bE, 0, 65536, 0);

    int koff = 128;   // staging byte offset for tile t+1
    #pragma unroll 1
    for (int i = 0; i < 7; ++i) {
        KT(0, 65536, 32768, 98304, koff, 1, VMW(0), 1); koff += 128;
        KT(32768, 98304, 0, 65536, koff, 1, VMW(0), 1); koff += 128;
    }
    KT(0, 65536, 32768, 98304, koff, 1, VMW(0), 1);     // tile 14, stages 15
    KT(32768, 98304, 0, 65536, 0, 0, (void)0, 0);       // tile 15

    // epilogue: C = out_scale * acc + bias
    // 32x32 C/D layout: col = l&31, row = (reg&3) + 8*(reg>>2) + 4*(l>>5)
    const float osc = qp[1];
    #pragma unroll
    for (int m_ = 0; m_ < 4; ++m_) {
        const int crow = row0 + wr * 128 + m_ * 32 + kg * 4;
        #pragma unroll
        for (int n_ = 0; n_ < 2; ++n_) {
            const int ccol = col0 + wc * 64 + n_ * 32 + rl;
            const float bv = bias[ccol];
            #pragma unroll
            for (int r = 0; r < 16; ++r) {
                const int row = crow + (r & 3) + 8 * (r >> 2);
                C[(size_t)row * N_TOT + ccol] = (float)acc[m_][n_][r] * osc + bv;
            }
        }
    }
}

extern "C" void kernel_launch(void* const* d_in, const int* in_sizes, int n_in,
                              void* d_out, int out_size, void* d_ws, size_t ws_size,
                              hipStream_t stream) {
    const float* x     = (const float*)d_in[0];
    const float* wgt   = (const float*)d_in[1];
    const float* alpha = (const float*)d_in[2];
    const float* bias  = (const float*)d_in[3];
    float* out = (float*)d_out;

    char* ws = (char*)d_ws;
    double* wsum = (double*)ws;               // 8 KB
    float* xmax  = (float*)(ws + 8192);       // 4 KB
    double* delta = (double*)(ws + 12288);
    float* qp     = (float*)(ws + 12304);     // [0]=127/max, [1]=alpha*max/127
    s8* xb = (s8*)(ws + 16384);               // 16 MB, row-major
    s8* wb = (s8*)(ws + 16384 + (size_t)X_COUNT);  // 16 MB, row-major

    tl_reduce<<<2048, 256, 0, stream>>>(wgt, x, wsum, xmax);
    tl_finalize<<<1, 256, 0, stream>>>(wsum, xmax, alpha, delta, qp);
    tl_quant<<<8192, 256, 0, stream>>>(wgt, x, delta, qp, wb, xb);
    tl_gemm_i8<<<(M_TOT / 256) * (N_TOT / 256), 512, 0, stream>>>(xb, wb, qp, bias, out);
}